// Round 1
// baseline (151.935 us; speedup 1.0000x reference)
//
#include <hip/hip_runtime.h>

#define NJ 7
static constexpr float DT_C   = 0.01f;
static constexpr float G_ACC_C = 9.81f;

// E = (R_fix @ Rodrigues(axis,q))^T, computed from precomputed sin/cos.
__device__ __forceinline__ void compute_E(const float* __restrict__ Rf,
                                          float ax, float ay, float az,
                                          float s, float c, float E[3][3]) {
    float oc = 1.0f - c;
    float K2xx = -(ay*ay + az*az);
    float K2yy = -(ax*ax + az*az);
    float K2zz = -(ax*ax + ay*ay);
    float K2xy = ax*ay, K2xz = ax*az, K2yz = ay*az;
    float R00 = 1.0f + oc*K2xx;
    float R01 = -s*az + oc*K2xy;
    float R02 =  s*ay + oc*K2xz;
    float R10 =  s*az + oc*K2xy;
    float R11 = 1.0f + oc*K2yy;
    float R12 = -s*ax + oc*K2yz;
    float R20 = -s*ay + oc*K2xz;
    float R21 =  s*ax + oc*K2yz;
    float R22 = 1.0f + oc*K2zz;
    // Rw = Rf @ R ; E = Rw^T  =>  E[i][j] = sum_k Rf[j*3+k] * R[k][i]
    E[0][0] = Rf[0]*R00 + Rf[1]*R10 + Rf[2]*R20;
    E[1][0] = Rf[0]*R01 + Rf[1]*R11 + Rf[2]*R21;
    E[2][0] = Rf[0]*R02 + Rf[1]*R12 + Rf[2]*R22;
    E[0][1] = Rf[3]*R00 + Rf[4]*R10 + Rf[5]*R20;
    E[1][1] = Rf[3]*R01 + Rf[4]*R11 + Rf[5]*R21;
    E[2][1] = Rf[3]*R02 + Rf[4]*R12 + Rf[5]*R22;
    E[0][2] = Rf[6]*R00 + Rf[7]*R10 + Rf[8]*R20;
    E[1][2] = Rf[6]*R01 + Rf[7]*R11 + Rf[8]*R21;
    E[2][2] = Rf[6]*R02 + Rf[7]*R12 + Rf[8]*R22;
}

extern "C" __global__ __launch_bounds__(256)
void aba_step_kernel(const float* __restrict__ x, const float* __restrict__ u,
                     const float* __restrict__ axes, const float* __restrict__ Rfix,
                     const float* __restrict__ pfix, const float* __restrict__ mass,
                     const float* __restrict__ com, const float* __restrict__ inertia,
                     float* __restrict__ out, int B)
{
    int b = blockIdx.x * blockDim.x + threadIdx.x;
    if (b >= B) return;

    float q[NJ], qd[NJ], tau[NJ];
    #pragma unroll
    for (int i = 0; i < NJ; ++i) {
        q[i]   = x[b*(2*NJ) + i];
        qd[i]  = x[b*(2*NJ) + NJ + i];
        tau[i] = u[b*NJ + i];
    }

    float sn[NJ], cn[NJ];
    float cl[NJ][6];     // bias (Coriolis) spatial vectors c_i
    float pU[NJ][6];     // pA_i during fwd/bwd; overwritten with U_i
    float dl[NJ], uul[NJ];

    // ---------------- forward velocity pass ----------------
    float v0=0.f, v1=0.f, v2=0.f, v3=0.f, v4=0.f, v5=0.f;
    #pragma unroll
    for (int i = 0; i < NJ; ++i) {
        float s, c;
        sincosf(q[i], &s, &c);
        sn[i] = s; cn[i] = c;
        float ax = axes[3*i+0], ay = axes[3*i+1], az = axes[3*i+2];
        float vJ0 = qd[i]*ax, vJ1 = qd[i]*ay, vJ2 = qd[i]*az;
        if (i == 0) {
            v0 = vJ0; v1 = vJ1; v2 = vJ2; v3 = 0.f; v4 = 0.f; v5 = 0.f;
        } else {
            float E[3][3];
            compute_E(Rfix + 9*i, ax, ay, az, s, c, E);
            float px = pfix[3*i], py = pfix[3*i+1], pz = pfix[3*i+2];
            // t = u - r x w
            float t0 = v3 - (py*v2 - pz*v1);
            float t1 = v4 - (pz*v0 - px*v2);
            float t2 = v5 - (px*v1 - py*v0);
            float nw0 = E[0][0]*v0 + E[0][1]*v1 + E[0][2]*v2;
            float nw1 = E[1][0]*v0 + E[1][1]*v1 + E[1][2]*v2;
            float nw2 = E[2][0]*v0 + E[2][1]*v1 + E[2][2]*v2;
            float nu0 = E[0][0]*t0 + E[0][1]*t1 + E[0][2]*t2;
            float nu1 = E[1][0]*t0 + E[1][1]*t1 + E[1][2]*t2;
            float nu2 = E[2][0]*t0 + E[2][1]*t1 + E[2][2]*t2;
            v0 = nw0 + vJ0; v1 = nw1 + vJ1; v2 = nw2 + vJ2;
            v3 = nu0; v4 = nu1; v5 = nu2;
        }
        // c_i = crm(v, vJ) with vJ linear part = 0: [w x vJw ; u x vJw]
        cl[i][0] = v1*vJ2 - v2*vJ1;
        cl[i][1] = v2*vJ0 - v0*vJ2;
        cl[i][2] = v0*vJ1 - v1*vJ0;
        cl[i][3] = v4*vJ2 - v5*vJ1;
        cl[i][4] = v5*vJ0 - v3*vJ2;
        cl[i][5] = v3*vJ1 - v4*vJ0;
        // Iv = I6_i @ v  (blocks: [[A, m*cx],[m*cx^T, m*I]])
        float m = mass[i];
        float cxx = com[3*i], cyy = com[3*i+1], czz = com[3*i+2];
        const float* In = inertia + 9*i;
        float cc = cxx*cxx + cyy*cyy + czz*czz;
        float A00 = In[0] + m*(cc - cxx*cxx);
        float A01 = In[1] - m*cxx*cyy;
        float A02 = In[2] - m*cxx*czz;
        float A10 = In[3] - m*cxx*cyy;
        float A11 = In[4] + m*(cc - cyy*cyy);
        float A12 = In[5] - m*cyy*czz;
        float A20 = In[6] - m*cxx*czz;
        float A21 = In[7] - m*cyy*czz;
        float A22 = In[8] + m*(cc - czz*czz);
        float n0 = A00*v0 + A01*v1 + A02*v2 + m*(cyy*v5 - czz*v4);
        float n1 = A10*v0 + A11*v1 + A12*v2 + m*(czz*v3 - cxx*v5);
        float n2 = A20*v0 + A21*v1 + A22*v2 + m*(cxx*v4 - cyy*v3);
        float f0 = m*(v1*czz - v2*cyy + v3);
        float f1 = m*(v2*cxx - v0*czz + v4);
        float f2 = m*(v0*cyy - v1*cxx + v5);
        // pA = crf(v, Iv) = [w x n + u x f ; w x f]
        pU[i][0] = v1*n2 - v2*n1 + v4*f2 - v5*f1;
        pU[i][1] = v2*n0 - v0*n2 + v5*f0 - v3*f2;
        pU[i][2] = v0*n1 - v1*n0 + v3*f1 - v4*f0;
        pU[i][3] = v1*f2 - v2*f1;
        pU[i][4] = v2*f0 - v0*f2;
        pU[i][5] = v0*f1 - v1*f0;
    }

    // ---------------- backward pass ----------------
    float P[6][6];   // propagated Xm^T Ia Xm term for level i-1
    #pragma unroll
    for (int r = 0; r < 6; ++r)
        #pragma unroll
        for (int c2 = 0; c2 < 6; ++c2) P[r][c2] = 0.0f;

    #pragma unroll
    for (int ii = 0; ii < NJ; ++ii) {
        const int i = NJ - 1 - ii;
        float m = mass[i];
        float cxx = com[3*i], cyy = com[3*i+1], czz = com[3*i+2];
        const float* In = inertia + 9*i;
        float cc = cxx*cxx + cyy*cyy + czz*czz;
        float IA[6][6];
        IA[0][0] = In[0] + m*(cc - cxx*cxx) + P[0][0];
        IA[0][1] = In[1] - m*cxx*cyy        + P[0][1];
        IA[0][2] = In[2] - m*cxx*czz        + P[0][2];
        IA[1][0] = In[3] - m*cxx*cyy        + P[1][0];
        IA[1][1] = In[4] + m*(cc - cyy*cyy) + P[1][1];
        IA[1][2] = In[5] - m*cyy*czz        + P[1][2];
        IA[2][0] = In[6] - m*cxx*czz        + P[2][0];
        IA[2][1] = In[7] - m*cyy*czz        + P[2][1];
        IA[2][2] = In[8] + m*(cc - czz*czz) + P[2][2];
        IA[0][3] = P[0][3];           IA[0][4] = -m*czz + P[0][4];  IA[0][5] =  m*cyy + P[0][5];
        IA[1][3] =  m*czz + P[1][3];  IA[1][4] = P[1][4];           IA[1][5] = -m*cxx + P[1][5];
        IA[2][3] = -m*cyy + P[2][3];  IA[2][4] =  m*cxx + P[2][4];  IA[2][5] = P[2][5];
        IA[3][0] = P[3][0];           IA[3][1] =  m*czz + P[3][1];  IA[3][2] = -m*cyy + P[3][2];
        IA[4][0] = -m*czz + P[4][0];  IA[4][1] = P[4][1];           IA[4][2] =  m*cxx + P[4][2];
        IA[5][0] =  m*cyy + P[5][0];  IA[5][1] = -m*cxx + P[5][1];  IA[5][2] = P[5][2];
        IA[3][3] = m + P[3][3];  IA[3][4] = P[3][4];      IA[3][5] = P[3][5];
        IA[4][3] = P[4][3];      IA[4][4] = m + P[4][4];  IA[4][5] = P[4][5];
        IA[5][3] = P[5][3];      IA[5][4] = P[5][4];      IA[5][5] = m + P[5][5];

        float ax = axes[3*i], ay = axes[3*i+1], az = axes[3*i+2];
        float U[6];
        #pragma unroll
        for (int r = 0; r < 6; ++r)
            U[r] = IA[r][0]*ax + IA[r][1]*ay + IA[r][2]*az;
        float d  = U[0]*ax + U[1]*ay + U[2]*az;
        float uu = tau[i] - (pU[i][0]*ax + pU[i][1]*ay + pU[i][2]*az);
        dl[i] = d; uul[i] = uu;
        float invd = 1.0f / d;

        if (i > 0) {
            // Ia = IA - U U^T / d   (overwrite IA)
            #pragma unroll
            for (int r = 0; r < 6; ++r)
                #pragma unroll
                for (int c2 = 0; c2 < 6; ++c2)
                    IA[r][c2] -= U[r]*U[c2]*invd;
            // pa = pA + Ia @ c + U*(uu/d)
            float k = uu*invd;
            float pa[6];
            #pragma unroll
            for (int r = 0; r < 6; ++r) {
                float acc = pU[i][r] + U[r]*k;
                #pragma unroll
                for (int c2 = 0; c2 < 6; ++c2) acc += IA[r][c2]*cl[i][c2];
                pa[r] = acc;
            }
            float E[3][3];
            compute_E(Rfix + 9*i, ax, ay, az, sn[i], cn[i], E);
            float px = pfix[3*i], py = pfix[3*i+1], pz = pfix[3*i+2];
            // F = -E @ skew(p)
            float F[3][3];
            #pragma unroll
            for (int r = 0; r < 3; ++r) {
                F[r][0] = E[r][2]*py - E[r][1]*pz;
                F[r][1] = E[r][0]*pz - E[r][2]*px;
                F[r][2] = E[r][1]*px - E[r][0]*py;
            }
            // prop = Xm^T Ia Xm with Xm=[[E,0],[F,E]], Ia=[[A,Bb],[Bb^T,C]]
            float G3[3][3], G4[3][3];
            #pragma unroll
            for (int r = 0; r < 3; ++r)
                #pragma unroll
                for (int c2 = 0; c2 < 3; ++c2) {
                    G3[r][c2] = IA[r][3]*E[0][c2] + IA[r][4]*E[1][c2] + IA[r][5]*E[2][c2];
                    G4[r][c2] = IA[3+r][3]*E[0][c2] + IA[3+r][4]*E[1][c2] + IA[3+r][5]*E[2][c2];
                }
            #pragma unroll
            for (int r = 0; r < 3; ++r)
                #pragma unroll
                for (int c2 = 0; c2 < 3; ++c2) {
                    P[r][3+c2] = E[0][r]*G3[0][c2] + E[1][r]*G3[1][c2] + E[2][r]*G3[2][c2]
                               + F[0][r]*G4[0][c2] + F[1][r]*G4[1][c2] + F[2][r]*G4[2][c2];
                    P[3+r][3+c2] = E[0][r]*G4[0][c2] + E[1][r]*G4[1][c2] + E[2][r]*G4[2][c2];
                }
            float G1[3][3], G2[3][3];
            #pragma unroll
            for (int r = 0; r < 3; ++r)
                #pragma unroll
                for (int c2 = 0; c2 < 3; ++c2) {
                    G1[r][c2] = IA[r][0]*E[0][c2] + IA[r][1]*E[1][c2] + IA[r][2]*E[2][c2]
                              + IA[r][3]*F[0][c2] + IA[r][4]*F[1][c2] + IA[r][5]*F[2][c2];
                    G2[r][c2] = IA[3+r][0]*E[0][c2] + IA[3+r][1]*E[1][c2] + IA[3+r][2]*E[2][c2]
                              + IA[3+r][3]*F[0][c2] + IA[3+r][4]*F[1][c2] + IA[3+r][5]*F[2][c2];
                }
            #pragma unroll
            for (int r = 0; r < 3; ++r)
                #pragma unroll
                for (int c2 = 0; c2 < 3; ++c2) {
                    P[r][c2] = E[0][r]*G1[0][c2] + E[1][r]*G1[1][c2] + E[2][r]*G1[2][c2]
                             + F[0][r]*G2[0][c2] + F[1][r]*G2[1][c2] + F[2][r]*G2[2][c2];
                }
            #pragma unroll
            for (int r = 0; r < 3; ++r)
                #pragma unroll
                for (int c2 = 0; c2 < 3; ++c2)
                    P[3+r][c2] = P[c2][3+r];   // symmetric bottom-left
            // pA_{i-1} += [E^T pa_ang + p x fE ; fE],  fE = E^T pa_lin
            float fE0 = E[0][0]*pa[3] + E[1][0]*pa[4] + E[2][0]*pa[5];
            float fE1 = E[0][1]*pa[3] + E[1][1]*pa[4] + E[2][1]*pa[5];
            float fE2 = E[0][2]*pa[3] + E[1][2]*pa[4] + E[2][2]*pa[5];
            float nP0 = E[0][0]*pa[0] + E[1][0]*pa[1] + E[2][0]*pa[2] + (py*fE2 - pz*fE1);
            float nP1 = E[0][1]*pa[0] + E[1][1]*pa[1] + E[2][1]*pa[2] + (pz*fE0 - px*fE2);
            float nP2 = E[0][2]*pa[0] + E[1][2]*pa[1] + E[2][2]*pa[2] + (px*fE1 - py*fE0);
            pU[i-1][0] += nP0; pU[i-1][1] += nP1; pU[i-1][2] += nP2;
            pU[i-1][3] += fE0; pU[i-1][4] += fE1; pU[i-1][5] += fE2;
        }
        // pA_i no longer needed -> store U_i in its slot
        #pragma unroll
        for (int r = 0; r < 6; ++r) pU[i][r] = U[r];
    }

    // ---------------- forward acceleration pass ----------------
    float a0=0.f, a1=0.f, a2=0.f, a3=0.f, a4=0.f, a5=G_ACC_C;
    #pragma unroll
    for (int i = 0; i < NJ; ++i) {
        float ax = axes[3*i], ay = axes[3*i+1], az = axes[3*i+2];
        float E[3][3];
        compute_E(Rfix + 9*i, ax, ay, az, sn[i], cn[i], E);
        float px = pfix[3*i], py = pfix[3*i+1], pz = pfix[3*i+2];
        float t0 = a3 - (py*a2 - pz*a1);
        float t1 = a4 - (pz*a0 - px*a2);
        float t2 = a5 - (px*a1 - py*a0);
        float ap0 = E[0][0]*a0 + E[0][1]*a1 + E[0][2]*a2 + cl[i][0];
        float ap1 = E[1][0]*a0 + E[1][1]*a1 + E[1][2]*a2 + cl[i][1];
        float ap2 = E[2][0]*a0 + E[2][1]*a1 + E[2][2]*a2 + cl[i][2];
        float ap3 = E[0][0]*t0 + E[0][1]*t1 + E[0][2]*t2 + cl[i][3];
        float ap4 = E[1][0]*t0 + E[1][1]*t1 + E[1][2]*t2 + cl[i][4];
        float ap5 = E[2][0]*t0 + E[2][1]*t1 + E[2][2]*t2 + cl[i][5];
        float Ud = pU[i][0]*ap0 + pU[i][1]*ap1 + pU[i][2]*ap2
                 + pU[i][3]*ap3 + pU[i][4]*ap4 + pU[i][5]*ap5;
        float qdd = (uul[i] - Ud) / dl[i];
        a0 = ap0 + qdd*ax; a1 = ap1 + qdd*ay; a2 = ap2 + qdd*az;
        a3 = ap3; a4 = ap4; a5 = ap5;
        float vn = qd[i] + DT_C*qdd;
        out[b*(2*NJ) + NJ + i] = vn;
        out[b*(2*NJ) + i]      = q[i] + DT_C*vn;
    }
}

extern "C" void kernel_launch(void* const* d_in, const int* in_sizes, int n_in,
                              void* d_out, int out_size, void* d_ws, size_t ws_size,
                              hipStream_t stream) {
    const float* x       = (const float*)d_in[0];
    const float* u       = (const float*)d_in[1];
    const float* axes    = (const float*)d_in[2];
    const float* Rfix    = (const float*)d_in[3];
    const float* pfix    = (const float*)d_in[4];
    const float* mass    = (const float*)d_in[5];
    const float* com     = (const float*)d_in[6];
    const float* inertia = (const float*)d_in[7];
    float* out = (float*)d_out;
    int B = in_sizes[0] / (2*NJ);
    int threads = 256;
    int blocks = (B + threads - 1) / threads;
    hipLaunchKernelGGL(aba_step_kernel, dim3(blocks), dim3(threads), 0, stream,
                       x, u, axes, Rfix, pfix, mass, com, inertia, out, B);
}